// Round 15
// baseline (39.537 us; speedup 1.0000x reference)
//
#include <hip/hip_runtime.h>
#include <math.h>

#define BB 32
#define SS 2048
#define HH 128
#define AA 8

typedef _Float16 h2 __attribute__((ext_vector_type(2)));
typedef _Float16 h8 __attribute__((ext_vector_type(8)));
typedef _Float16 f16x8 __attribute__((ext_vector_type(8)));
typedef _Float16 f16x4 __attribute__((ext_vector_type(4)));
typedef float f32x4 __attribute__((ext_vector_type(4)));

// ws layout:
//   bfrag:  [12][64] uint4 (12288 B) — u prepacked as MFMA B-fragments:
//           bfrag[kk][lane] elem j = B[k][c], k = kk*32+(lane>>4)*8+j
//           (k = w*128+d), c = lane&15 (zero for c>=8)
//   E:      [B][A][S]     524288 floats (masked exp(score), unnormalized)
//   Zpart:  [B][A][32]    8192
//   pools:  [B][32][A][H] 1048576 (unnormalized partial context sums)

// R11-proven prep: 8 blocks x 128 threads.
__global__ __launch_bounds__(128) void prep_kernel(const float* __restrict__ embed,
                                                   const float* __restrict__ proj,
                                                   uint4* __restrict__ bfrag) {
    __shared__ float ua[HH][3];   // u for this aspect: [d][w]
    int a = blockIdx.x;           // 0..7
    int d = threadIdx.x;          // 0..127
    const float* P = proj + ((size_t)a * HH + d) * HH;  // aspProj[a][d][:]
    const float* E = embed + a * (3 * HH);              // embedR[a][h][w] = E[h*3+w]
    float a0 = 0.f, a1 = 0.f, a2 = 0.f;
    for (int h = 0; h < HH; ++h) {
        float x = P[h];
        a0 += x * E[h * 3 + 0];   // E loads wave-uniform -> scalar cache
        a1 += x * E[h * 3 + 1];
        a2 += x * E[h * 3 + 2];
    }
    ua[d][0] = a0; ua[d][1] = a1; ua[d][2] = a2;
    __syncthreads();

    for (int i = d; i < 96; i += 128) {
        int kk = i >> 3, e = i & 7;
        f16x8 v = {0, 0, 0, 0, 0, 0, 0, 0};
        int lane;
        if (e < 4) {
            int q = e;
            lane = q * 16 + a;
            #pragma unroll
            for (int j = 0; j < 8; ++j) {
                int k = kk * 32 + q * 8 + j;
                int w = k >> 7, dd = k & 127;
                v[j] = (_Float16)ua[dd][w];
            }
        } else {
            lane = (e - 4) * 16 + a + 8;   // zero columns 8..15
        }
        bfrag[kk * 64 + lane] = __builtin_bit_cast(uint4, v);
    }
}

// R14-proven tile: scores via 16x16x32 MFMA; E/Zpart in-register; pool via
// 16x16x16 MFMA with in-register A (score D layout == pool A layout).
__global__ __launch_bounds__(256, 4) void tile_kernel(const float* __restrict__ doc,
                                                      const int* __restrict__ mask,
                                                      const uint4* __restrict__ bfrag,
                                                      float* __restrict__ E,
                                                      float* __restrict__ Zpart,
                                                      float* __restrict__ pools) {
    // dt [66][72] h2 (19008 B) + zredN [4][16] f32 (256 B); cs2 overlays dt.
    __shared__ __align__(16) unsigned char smraw[19264];
    h2*    dt    = (h2*)smraw;
    float* zredN = (float*)(smraw + 19008);

    int t = threadIdx.x;
    int lane = t & 63, wave = t >> 6;
    int tile = blockIdx.x;   // 0..31, 64 s each
    int b = blockIdx.y;
    int s0 = tile * 64;

    // ---- stage rows s0-1 .. s0+64 as f16 (zero outside [0,S)), stride 72 h2 ----
    for (int idx = t; idx < 66 * 16; idx += 256) {
        int row = idx >> 4, c = idx & 15;   // c: 8-float chunk
        int srow = s0 - 1 + row;
        h8 hv = {0, 0, 0, 0, 0, 0, 0, 0};
        if (srow >= 0 && srow < SS) {
            const float4* src = (const float4*)(doc + ((size_t)b * SS + srow) * HH + c * 8);
            float4 v0 = src[0], v1 = src[1];
            hv[0] = (_Float16)v0.x; hv[1] = (_Float16)v0.y;
            hv[2] = (_Float16)v0.z; hv[3] = (_Float16)v0.w;
            hv[4] = (_Float16)v1.x; hv[5] = (_Float16)v1.y;
            hv[6] = (_Float16)v1.z; hv[7] = (_Float16)v1.w;
        }
        *(h8*)(dt + row * 72 + c * 4) = hv;
    }

    // ---- B fragments for scores: 12 x 16B per lane (L2-hot) ----
    f16x8 bf[12];
    #pragma unroll
    for (int kk = 0; kk < 12; ++kk)
        bf[kk] = __builtin_bit_cast(f16x8, bfrag[kk * 64 + lane]);
    __syncthreads();   // dt ready

    // ---- scores: wave covers s rows wave*16 .. wave*16+15 ----
    f32x4 acc = {0.f, 0.f, 0.f, 0.f};
    #pragma unroll
    for (int kk = 0; kk < 12; ++kk) {
        int w = kk >> 2;
        int row = wave * 16 + (lane & 15) + w;
        int colh2 = (kk & 3) * 16 + (lane >> 4) * 4;
        f16x8 af = *(const f16x8*)(dt + row * 72 + colh2);
        acc = __builtin_amdgcn_mfma_f32_16x16x32_f16(af, bf[kk], acc, 0, 0, 0);
    }

    // ---- E write + in-register A-frag (af4) + in-register Z partial ----
    const int* mrow = mask + (size_t)b * SS + s0;
    int a = lane & 15;
    int rbase = wave * 16 + (lane >> 4) * 4;
    f16x4 af4;
    float4 ev;
    float* evp = (float*)&ev;
    float zsum = 0.f;
    #pragma unroll
    for (int jj = 0; jj < 4; ++jj) {
        int sl2 = rbase + jj;
        float e = (a < 8 && mrow[sl2]) ? __expf(acc[jj]) : 0.f;
        evp[jj] = e;
        af4[jj] = (_Float16)e;
        zsum += e;
    }
    if (a < 8)
        *(float4*)(E + ((size_t)(b * AA + a)) * SS + s0 + rbase) = ev;
    zsum += __shfl_xor(zsum, 16);   // combine the four (lane>>4) s-groups
    zsum += __shfl_xor(zsum, 32);
    if (lane < 16) zredN[wave * 16 + lane] = zsum;   // per-a per-wave Z

    // ---- pool MFMAs: per wave, K=16 (its own s), 8 d-tiles of 16 ----
    const _Float16* dtf = (const _Float16*)dt;
    f32x4 pc[8];
    #pragma unroll
    for (int i = 0; i < 8; ++i) pc[i] = (f32x4){0.f, 0.f, 0.f, 0.f};
    int srow0 = 1 + rbase;
    #pragma unroll
    for (int dtile = 0; dtile < 8; ++dtile) {
        f16x4 bfp;
        #pragma unroll
        for (int j = 0; j < 4; ++j)
            bfp[j] = dtf[(srow0 + j) * 144 + dtile * 16 + a];
        pc[dtile] = __builtin_amdgcn_mfma_f32_16x16x16f16(af4, bfp, pc[dtile], 0, 0, 0);
    }
    __syncthreads();   // all dt reads + all zredN writes done

    // pool D layout: col = lane&15 = d_in_tile, row = (lane>>4)*4+reg = a
    float* cs2 = (float*)smraw;   // [4 wave][8 a][128 d] = 16384 B < 19008
    if ((lane >> 4) < 2) {
        int ab = (lane >> 4) * 4;
        #pragma unroll
        for (int dtile = 0; dtile < 8; ++dtile) {
            int d = dtile * 16 + a;
            #pragma unroll
            for (int r = 0; r < 4; ++r)
                cs2[wave * 1024 + (ab + r) * 128 + d] = pc[dtile][r];
        }
    }
    if (t < 8) {
        float z = (zredN[0 * 16 + t] + zredN[1 * 16 + t]) +
                  (zredN[2 * 16 + t] + zredN[3 * 16 + t]);
        Zpart[((size_t)(b * AA + t)) * 32 + tile] = z;
    }
    __syncthreads();
    for (int oi = t; oi < 1024; oi += 256) {
        int aa = oi >> 7, d = oi & 127;
        float v = (cs2[0 * 1024 + aa * 128 + d] + cs2[1 * 1024 + aa * 128 + d]) +
                  (cs2[2 * 1024 + aa * 128 + d] + cs2[3 * 1024 + aa * 128 + d]);
        pools[(((size_t)(b * 32 + tile)) * AA + aa) * HH + d] = v;
    }
}

// NEW finalize: one block per (b,a) — grid (8, 32), 256 blocks.
//   Z: 32 parallel lane loads + fixed-order butterfly reduce (no serial chain).
//   attn = E*invZ: 2 x float4 per thread, coalesced along s.
//   ctx[d] = sum_c pools[b][c][a][d] (pools read exactly once).
//   rep = ctx @ proj[a] via the proven 2-half hred pattern.
__global__ __launch_bounds__(256) void finalize_kernel(const float* __restrict__ E,
                                                       const float* __restrict__ Zpart,
                                                       const float* __restrict__ pools,
                                                       const float* __restrict__ proj,
                                                       float* __restrict__ attn,
                                                       float* __restrict__ rep) {
    __shared__ float ctx[128];
    __shared__ float hred[2][128];
    __shared__ float invzs;
    int t = threadIdx.x;
    int a = blockIdx.x;   // 0..7
    int b = blockIdx.y;   // 0..31

    if (t < 64) {         // wave 0 exactly: butterfly over 32 loaded + 32 zero lanes
        float z = (t < 32) ? Zpart[((size_t)(b * AA + a)) * 32 + t] : 0.f;
        z += __shfl_xor(z, 1);  z += __shfl_xor(z, 2);  z += __shfl_xor(z, 4);
        z += __shfl_xor(z, 8);  z += __shfl_xor(z, 16); z += __shfl_xor(z, 32);
        if (t == 0) invzs = 1.0f / z;
    }
    __syncthreads();
    float invz = invzs;

    // attn: 2048 floats for (b,a)
    {
        size_t base = ((size_t)(b * AA + a)) * SS;
        const float4* Ev = (const float4*)(E + base);
        float4* Av = (float4*)(attn + base);
        #pragma unroll
        for (int r = 0; r < 2; ++r) {
            float4 v = Ev[t + r * 256];
            v.x *= invz; v.y *= invz; v.z *= invz; v.w *= invz;
            Av[t + r * 256] = v;
        }
    }

    // ctx[d] = invz * sum_c pools[b][c][a][d]
    if (t < 128) {
        float v = 0.f;
        for (int c = 0; c < 32; ++c)
            v += pools[(((size_t)(b * 32 + c)) * AA + a) * HH + t];
        ctx[t] = v * invz;
    }
    __syncthreads();

    // rep[h] = sum_d ctx[d] * proj[a][d][h]
    {
        int h = t & 127, dh = t >> 7;
        float v = 0.f;
        for (int d = dh * 64; d < dh * 64 + 64; ++d)
            v += ctx[d] * proj[((size_t)a * HH + d) * HH + h];
        hred[dh][h] = v;
    }
    __syncthreads();
    if (t < 128)
        rep[((size_t)(b * AA + a)) * HH + t] = hred[0][t] + hred[1][t];
}

extern "C" void kernel_launch(void* const* d_in, const int* in_sizes, int n_in,
                              void* d_out, int out_size, void* d_ws, size_t ws_size,
                              hipStream_t stream) {
    const float* doc   = (const float*)d_in[0];   // [32][2048][128]
    const int*   mask  = (const int*)d_in[1];     // [32][2048]
    const float* embed = (const float*)d_in[2];   // [8][384]
    const float* proj  = (const float*)d_in[3];   // [8][128][128]

    float* out  = (float*)d_out;
    float* attn = out;                             // [32][8][2048]
    float* rep  = out + (size_t)BB * AA * SS;      // [32][8][128]

    uint4* bfrag = (uint4*)d_ws;                   // 12288 B of the 16 KB slot
    float* E     = (float*)d_ws + 4096;
    float* Zp    = E + (size_t)BB * AA * SS;
    float* pools = Zp + (size_t)BB * AA * 32;

    prep_kernel<<<8, 128, 0, stream>>>(embed, proj, bfrag);
    tile_kernel<<<dim3(32, 32), 256, 0, stream>>>(doc, mask, bfrag, E, Zp, pools);
    finalize_kernel<<<dim3(8, 32), 256, 0, stream>>>(E, Zp, pools, proj, attn, rep);
}

// Round 16
// 27.264 us; speedup vs baseline: 1.4501x; 1.4501x over previous
//
#include <hip/hip_runtime.h>
#include <math.h>

#define BB 32
#define SS 2048
#define HH 128
#define AA 8

typedef _Float16 h2 __attribute__((ext_vector_type(2)));
typedef _Float16 h8 __attribute__((ext_vector_type(8)));
typedef _Float16 f16x8 __attribute__((ext_vector_type(8)));
typedef _Float16 f16x4 __attribute__((ext_vector_type(4)));
typedef float f32x4 __attribute__((ext_vector_type(4)));

// ws layout:
//   bfrag:  [12][64] uint4 (12288 B) — u prepacked as MFMA B-fragments:
//           bfrag[kk][lane] elem j = B[k][c], k = kk*32+(lane>>4)*8+j
//           (k = w*128+d), c = lane&15 (zero for c>=8)
//   E:      [B][A][S]     524288 floats (masked exp(score), unnormalized)
//   Zpart:  [B][A][32]    8192
//   pools:  [B][32][A][H] 1048576 (unnormalized partial context sums)

// R11-proven prep: 8 blocks x 128 threads.
__global__ __launch_bounds__(128) void prep_kernel(const float* __restrict__ embed,
                                                   const float* __restrict__ proj,
                                                   uint4* __restrict__ bfrag) {
    __shared__ float ua[HH][3];   // u for this aspect: [d][w]
    int a = blockIdx.x;           // 0..7
    int d = threadIdx.x;          // 0..127
    const float* P = proj + ((size_t)a * HH + d) * HH;  // aspProj[a][d][:]
    const float* E = embed + a * (3 * HH);              // embedR[a][h][w] = E[h*3+w]
    float a0 = 0.f, a1 = 0.f, a2 = 0.f;
    for (int h = 0; h < HH; ++h) {
        float x = P[h];
        a0 += x * E[h * 3 + 0];   // E loads wave-uniform -> scalar cache
        a1 += x * E[h * 3 + 1];
        a2 += x * E[h * 3 + 2];
    }
    ua[d][0] = a0; ua[d][1] = a1; ua[d][2] = a2;
    __syncthreads();

    for (int i = d; i < 96; i += 128) {
        int kk = i >> 3, e = i & 7;
        f16x8 v = {0, 0, 0, 0, 0, 0, 0, 0};
        int lane;
        if (e < 4) {
            int q = e;
            lane = q * 16 + a;
            #pragma unroll
            for (int j = 0; j < 8; ++j) {
                int k = kk * 32 + q * 8 + j;
                int w = k >> 7, dd = k & 127;
                v[j] = (_Float16)ua[dd][w];
            }
        } else {
            lane = (e - 4) * 16 + a + 8;   // zero columns 8..15
        }
        bfrag[kk * 64 + lane] = __builtin_bit_cast(uint4, v);
    }
}

// R14-proven tile: scores via 16x16x32 MFMA; E/Zpart in-register; pool via
// 16x16x16 MFMA with in-register A (score D layout == pool A layout).
__global__ __launch_bounds__(256, 4) void tile_kernel(const float* __restrict__ doc,
                                                      const int* __restrict__ mask,
                                                      const uint4* __restrict__ bfrag,
                                                      float* __restrict__ E,
                                                      float* __restrict__ Zpart,
                                                      float* __restrict__ pools) {
    // dt [66][72] h2 (19008 B) + zredN [4][16] f32 (256 B); cs2 overlays dt.
    __shared__ __align__(16) unsigned char smraw[19264];
    h2*    dt    = (h2*)smraw;
    float* zredN = (float*)(smraw + 19008);

    int t = threadIdx.x;
    int lane = t & 63, wave = t >> 6;
    int tile = blockIdx.x;   // 0..31, 64 s each
    int b = blockIdx.y;
    int s0 = tile * 64;

    // ---- stage rows s0-1 .. s0+64 as f16 (zero outside [0,S)), stride 72 h2 ----
    for (int idx = t; idx < 66 * 16; idx += 256) {
        int row = idx >> 4, c = idx & 15;   // c: 8-float chunk
        int srow = s0 - 1 + row;
        h8 hv = {0, 0, 0, 0, 0, 0, 0, 0};
        if (srow >= 0 && srow < SS) {
            const float4* src = (const float4*)(doc + ((size_t)b * SS + srow) * HH + c * 8);
            float4 v0 = src[0], v1 = src[1];
            hv[0] = (_Float16)v0.x; hv[1] = (_Float16)v0.y;
            hv[2] = (_Float16)v0.z; hv[3] = (_Float16)v0.w;
            hv[4] = (_Float16)v1.x; hv[5] = (_Float16)v1.y;
            hv[6] = (_Float16)v1.z; hv[7] = (_Float16)v1.w;
        }
        *(h8*)(dt + row * 72 + c * 4) = hv;
    }

    // ---- B fragments for scores: 12 x 16B per lane (L2-hot) ----
    f16x8 bf[12];
    #pragma unroll
    for (int kk = 0; kk < 12; ++kk)
        bf[kk] = __builtin_bit_cast(f16x8, bfrag[kk * 64 + lane]);
    __syncthreads();   // dt ready

    // ---- scores: wave covers s rows wave*16 .. wave*16+15 ----
    f32x4 acc = {0.f, 0.f, 0.f, 0.f};
    #pragma unroll
    for (int kk = 0; kk < 12; ++kk) {
        int w = kk >> 2;
        int row = wave * 16 + (lane & 15) + w;
        int colh2 = (kk & 3) * 16 + (lane >> 4) * 4;
        f16x8 af = *(const f16x8*)(dt + row * 72 + colh2);
        acc = __builtin_amdgcn_mfma_f32_16x16x32_f16(af, bf[kk], acc, 0, 0, 0);
    }

    // ---- E write + in-register A-frag (af4) + in-register Z partial ----
    const int* mrow = mask + (size_t)b * SS + s0;
    int a = lane & 15;
    int rbase = wave * 16 + (lane >> 4) * 4;
    f16x4 af4;
    float4 ev;
    float* evp = (float*)&ev;
    float zsum = 0.f;
    #pragma unroll
    for (int jj = 0; jj < 4; ++jj) {
        int sl2 = rbase + jj;
        float e = (a < 8 && mrow[sl2]) ? __expf(acc[jj]) : 0.f;
        evp[jj] = e;
        af4[jj] = (_Float16)e;
        zsum += e;
    }
    if (a < 8)
        *(float4*)(E + ((size_t)(b * AA + a)) * SS + s0 + rbase) = ev;
    zsum += __shfl_xor(zsum, 16);   // combine the four (lane>>4) s-groups
    zsum += __shfl_xor(zsum, 32);
    if (lane < 16) zredN[wave * 16 + lane] = zsum;   // per-a per-wave Z

    // ---- pool MFMAs: per wave, K=16 (its own s), 8 d-tiles of 16 ----
    const _Float16* dtf = (const _Float16*)dt;
    f32x4 pc[8];
    #pragma unroll
    for (int i = 0; i < 8; ++i) pc[i] = (f32x4){0.f, 0.f, 0.f, 0.f};
    int srow0 = 1 + rbase;
    #pragma unroll
    for (int dtile = 0; dtile < 8; ++dtile) {
        f16x4 bfp;
        #pragma unroll
        for (int j = 0; j < 4; ++j)
            bfp[j] = dtf[(srow0 + j) * 144 + dtile * 16 + a];
        pc[dtile] = __builtin_amdgcn_mfma_f32_16x16x16f16(af4, bfp, pc[dtile], 0, 0, 0);
    }
    __syncthreads();   // all dt reads + all zredN writes done

    // pool D layout: col = lane&15 = d_in_tile, row = (lane>>4)*4+reg = a
    float* cs2 = (float*)smraw;   // [4 wave][8 a][128 d] = 16384 B < 19008
    if ((lane >> 4) < 2) {
        int ab = (lane >> 4) * 4;
        #pragma unroll
        for (int dtile = 0; dtile < 8; ++dtile) {
            int d = dtile * 16 + a;
            #pragma unroll
            for (int r = 0; r < 4; ++r)
                cs2[wave * 1024 + (ab + r) * 128 + d] = pc[dtile][r];
        }
    }
    if (t < 8) {
        float z = (zredN[0 * 16 + t] + zredN[1 * 16 + t]) +
                  (zredN[2 * 16 + t] + zredN[3 * 16 + t]);
        Zpart[((size_t)(b * AA + t)) * 32 + tile] = z;
    }
    __syncthreads();
    for (int oi = t; oi < 1024; oi += 256) {
        int aa = oi >> 7, d = oi & 127;
        float v = (cs2[0 * 1024 + aa * 128 + d] + cs2[1 * 1024 + aa * 128 + d]) +
                  (cs2[2 * 1024 + aa * 128 + d] + cs2[3 * 1024 + aa * 128 + d]);
        pools[(((size_t)(b * 32 + tile)) * AA + aa) * HH + d] = v;
    }
}

// R11-proven finalize: per (b, chunk): invZ from Zpart; attn = E*invZ for the
// 64-s chunk; plus a 32-h slice of rep for aspect a = chunk&7 (hq = chunk>>3).
// (4 blocks/CU TLP beats the "minimal-traffic" 256-block variant — R15 lesson.)
__global__ __launch_bounds__(256) void finalize_kernel(const float* __restrict__ E,
                                                       const float* __restrict__ Zpart,
                                                       const float* __restrict__ pools,
                                                       const float* __restrict__ proj,
                                                       float* __restrict__ attn,
                                                       float* __restrict__ rep) {
    __shared__ float zbuf[256];
    __shared__ float invZ[8];
    __shared__ float ctxp[2][128];
    __shared__ float ctx[128];
    __shared__ float seg[8][32];
    int t = threadIdx.x;
    int ck = blockIdx.x;     // 0..31
    int b = blockIdx.y;
    int a_rep = ck & 7, hq = ck >> 3;

    zbuf[t] = Zpart[((size_t)(b * AA + (t >> 5))) * 32 + (t & 31)];
    __syncthreads();
    if (t < 8) {
        float z = 0.f;
        #pragma unroll
        for (int k = 0; k < 32; ++k) z += zbuf[t * 32 + k];
        invZ[t] = 1.0f / z;
    }
    __syncthreads();

    for (int oi = t; oi < 512; oi += 256) {
        int a = oi >> 6, s = oi & 63;
        size_t idx = ((size_t)(b * AA + a)) * SS + ck * 64 + s;
        attn[idx] = E[idx] * invZ[a];
    }

    {
        int d = t & 127, half = t >> 7;
        float v = 0.f;
        for (int c = half * 16; c < half * 16 + 16; ++c)
            v += pools[(((size_t)(b * 32 + c)) * AA + a_rep) * HH + d];
        ctxp[half][d] = v;
    }
    __syncthreads();
    if (t < 128) ctx[t] = (ctxp[0][t] + ctxp[1][t]) * invZ[a_rep];
    __syncthreads();

    {
        int h = hq * 32 + (t & 31), sg = t >> 5;
        float v = 0.f;
        for (int d = sg * 16; d < sg * 16 + 16; ++d)
            v += ctx[d] * proj[((size_t)a_rep * HH + d) * HH + h];
        seg[sg][t & 31] = v;
    }
    __syncthreads();
    if (t < 32) {
        float v = 0.f;
        #pragma unroll
        for (int sg = 0; sg < 8; ++sg) v += seg[sg][t];
        rep[((size_t)(b * AA + a_rep)) * HH + hq * 32 + t] = v;
    }
}

extern "C" void kernel_launch(void* const* d_in, const int* in_sizes, int n_in,
                              void* d_out, int out_size, void* d_ws, size_t ws_size,
                              hipStream_t stream) {
    const float* doc   = (const float*)d_in[0];   // [32][2048][128]
    const int*   mask  = (const int*)d_in[1];     // [32][2048]
    const float* embed = (const float*)d_in[2];   // [8][384]
    const float* proj  = (const float*)d_in[3];   // [8][128][128]

    float* out  = (float*)d_out;
    float* attn = out;                             // [32][8][2048]
    float* rep  = out + (size_t)BB * AA * SS;      // [32][8][128]

    uint4* bfrag = (uint4*)d_ws;                   // 12288 B of the 16 KB slot
    float* E     = (float*)d_ws + 4096;
    float* Zp    = E + (size_t)BB * AA * SS;
    float* pools = Zp + (size_t)BB * AA * 32;

    prep_kernel<<<8, 128, 0, stream>>>(embed, proj, bfrag);
    tile_kernel<<<dim3(32, 32), 256, 0, stream>>>(doc, mask, bfrag, E, Zp, pools);
    finalize_kernel<<<dim3(32, 32), 256, 0, stream>>>(E, Zp, pools, proj, attn, rep);
}